// Round 23
// baseline (148.611 us; speedup 1.0000x reference)
//
#include <hip/hip_runtime.h>
#include <math.h>

#define NN 307
#define UU 100
#define DD 3
#define UP 104          // padded f16 activation row stride (208 B, 16B-aligned)
#define UNIT_W 14336    // f16 elements per packed weight unit (4*7*64*8 = 112x128)
#define HCAP 2560       // per-chunk edge capacity in gat2h (half-sample slice)
#define GT 1024         // gat2h_k block size (16 waves; VGPR 32 fits 64 budget)
#define NGRP (GT / 16)
#define PACK_BLOCKS 280 // 280*256 = 71680 = 5*UNIT_W exact

typedef _Float16 f16;
typedef f16  f16x2 __attribute__((ext_vector_type(2)));
typedef f16  f16x4 __attribute__((ext_vector_type(4)));
typedef f16  f16x8 __attribute__((ext_vector_type(8)));
typedef float f32x4 __attribute__((ext_vector_type(4)));
typedef unsigned short u16;

// ---------------------------------------------------------------------------
// prep_k: merged pack_w (blocks [0,280)) + csr_count (blocks [280,587)).
// ---------------------------------------------------------------------------
__global__ __launch_bounds__(256)
void prep_k(const float* __restrict__ Wl, const float* __restrict__ Wr,
            const float* __restrict__ Wg1, const float* __restrict__ Wg2,
            f16* __restrict__ Wp,
            const int* __restrict__ dst, int E, int* offs)
{
    if (blockIdx.x < PACK_BLOCKS) {
        const int idx = blockIdx.x * 256 + threadIdx.x;
        const int u   = idx / UNIT_W;
        const int rem = idx - u * UNIT_W;
        const int e   = rem & 7;
        const int l   = (rem >> 3) & 63;
        const int sj  = rem >> 9;
        const int s   = sj / 7, j = sj - 7 * s;
        const int col = j * 16 + (l & 15);
        const int k   = (s * 4 + (l >> 4)) * 8 + e;
        float v = 0.f;
        if (col < UU && k < UU + DD) {
            if (u == 0)      v = Wl[k * UU + col];
            else if (u == 1) v = Wr[k * UU + col];
            else {
                const int kk = (k < UU) ? (k + DD) : (k - UU);
                if (u == 2)      v = Wg1[kk * (2 * UU) + col];
                else if (u == 3) v = Wg1[kk * (2 * UU) + UU + col];
                else             v = Wg2[kk * UU + col];
            }
        }
        Wp[idx] = (f16)v;
    } else {
        const int d = blockIdx.x - PACK_BLOCKS;     // 0..NN-1
        if (threadIdx.x >= 64) return;              // 1 wave does the count
        const int lane = threadIdx.x;
        const int Etot = E + NN;
        int c = 0;
        for (int base = 0; base < Etot; base += 64) {
            const int e = base + lane;
            if (e < Etot) {
                const int de = (e < E) ? dst[e] : (e - E);
                c += (de == d) ? 1 : 0;
            }
        }
        #pragma unroll
        for (int m = 1; m < 64; m <<= 1) c += __shfl_xor(c, m, 64);
        if (lane == 0) {
            offs[d + 1] = c;
            if (d == 0) offs[0] = 0;
        }
    }
}

// Parallel Hillis-Steele scan over the 307 counts (1 block, 512 threads).
__global__ __launch_bounds__(512)
void csr_scan_k(int* offs)
{
    __shared__ int c[512];
    const int t = threadIdx.x;
    c[t] = (t < NN) ? offs[t + 1] : 0;
    __syncthreads();
    #pragma unroll
    for (int off = 1; off < 512; off <<= 1) {
        const int v = (t >= off) ? c[t - off] : 0;
        __syncthreads();
        c[t] += v;
        __syncthreads();
    }
    if (t < NN) offs[t + 1] = c[t];
    if (t == 0) offs[0] = 0;
}

__global__ __launch_bounds__(64)
void csr_fill_k(const int* __restrict__ src, const int* __restrict__ dst,
                int E, const int* __restrict__ offs,
                int* eidx, int* ddst)
{
    const int d = blockIdx.x;
    const int lane = threadIdx.x;
    const int Etot = E + NN;
    int w = offs[d];
    for (int base = 0; base < Etot; base += 64) {
        const int e = base + lane;
        bool match = false;
        int se = 0;
        if (e < Etot) {
            const int de = (e < E) ? dst[e] : (e - E);
            se           = (e < E) ? src[e] : (e - E);
            match = (de == d);
        }
        const unsigned long long mask = __ballot(match);
        if (match) {
            const int pos = w + __popcll(mask & ((1ULL << lane) - 1ULL));
            eidx[pos] = se;
            ddst[pos] = d;
        }
        w += __popcll(mask);
    }
}

// ---------------------------------------------------------------------------
// MFMA helper, barrier-free (global W loads must pipeline — r15/r18 lesson).
// ---------------------------------------------------------------------------
__device__ __forceinline__ void mma_unit_nb(const f16x8 (&af)[4],
                                            const f16* __restrict__ Wu,
                                            int l, f32x4 (&acc)[7])
{
    #pragma unroll
    for (int s = 0; s < 4; ++s)
        #pragma unroll
        for (int j = 0; j < 7; ++j) {
            const f16x8 bv = *(const f16x8*)(Wu + (((s * 7 + j) * 64 + l) << 3));
            acc[j] = __builtin_amdgcn_mfma_f32_16x16x32_f16(af[s], bv, acc[j], 0, 0, 0);
        }
}

__device__ __forceinline__ void z7(f32x4 (&acc)[7])
{
    #pragma unroll
    for (int j = 0; j < 7; ++j) acc[j] = (f32x4)0.f;
}

__device__ __forceinline__ float fast_sigmoid(float x)
{
    return __fdividef(1.f, 1.f + __expf(-x));
}

__device__ __forceinline__ float fast_tanh(float x)
{
    return 1.f - __fdividef(2.f, __expf(2.f * x) + 1.f);
}

// ---------------------------------------------------------------------------
// K0: xl/xr GEMM, LDS-free, high occupancy (r19-validated, unchanged).
// ---------------------------------------------------------------------------
__global__ __launch_bounds__(256, 4)
void gemm_xlxr_k(const float* __restrict__ state, const float* __restrict__ inp,
                 const f16* __restrict__ Wp,
                 f16* __restrict__ xl, f16* __restrict__ xr, int M)
{
    const int tid = threadIdx.x;
    const int w = tid >> 6, l = tid & 63, lr = l & 15, lk = l >> 4;
    const int rb = blockIdx.x * 64 + w * 16;
    int crow = rb + lr; if (crow >= M) crow = M - 1;
    const float* bf = state + (size_t)crow * UU;

    f16x8 af[4];
    #pragma unroll
    for (int s = 0; s < 3; ++s) {
        const int kb = s * 4 + lk;
        const float4 x0 = *(const float4*)(bf + kb * 8);
        const float4 x1 = *(const float4*)(bf + kb * 8 + 4);
        f16x8 v;
        v[0]=(f16)x0.x; v[1]=(f16)x0.y; v[2]=(f16)x0.z; v[3]=(f16)x0.w;
        v[4]=(f16)x1.x; v[5]=(f16)x1.y; v[6]=(f16)x1.z; v[7]=(f16)x1.w;
        af[s] = v;
    }
    {
        f16x8 v = (f16x8)(f16)0.f;
        if (lk == 0) {
            const float4 x0 = *(const float4*)(bf + 96);
            v[0]=(f16)x0.x; v[1]=(f16)x0.y; v[2]=(f16)x0.z; v[3]=(f16)x0.w;
            v[4] = (f16)inp[(size_t)crow * DD + 0];
            v[5] = (f16)inp[(size_t)crow * DD + 1];
            v[6] = (f16)inp[(size_t)crow * DD + 2];
            v[7] = (f16)0.f;
        }
        af[3] = v;
    }

    #pragma unroll
    for (int u = 0; u < 2; ++u) {
        f32x4 acc[7];
        z7(acc);
        mma_unit_nb(af, Wp + (size_t)u * UNIT_W, l, acc);
        f16* dst = u ? xr : xl;
        #pragma unroll
        for (int j = 0; j < 7; ++j) {
            const int col = j * 16 + lr;
            if (col >= UU) continue;
            #pragma unroll
            for (int r = 0; r < 4; ++r) {
                const int row = rb + lk * 4 + r;
                if (row < M) dst[(size_t)row * UP + col] = (f16)acc[j][r];
            }
        }
    }
}

// ---------------------------------------------------------------------------
// K1: GAT P2-P4, half-sample blocks, 1024 threads (r20-validated: VGPR 32,
// 2 blocks/CU = 32 waves/CU). xr rows read from global (CSR d-locality).
// ---------------------------------------------------------------------------
__global__ __launch_bounds__(GT, 8)
void gat2h_k(const f16* __restrict__ xl, const f16* __restrict__ xr,
             const int* __restrict__ offs, const int* __restrict__ eidx,
             const int* __restrict__ ddst,
             const float* __restrict__ att, const float* __restrict__ gb,
             const float* __restrict__ bgc,
             f16* __restrict__ stg)
{
    __shared__ f16   xl_s[NN * UP];    // 63856 B
    __shared__ float sc_s[HCAP];       // 10240 B
    __shared__ u16   ei_s[HCAP];       // 5120 B
    __shared__ f16   att_s[UP];        // 208 B

    const int b   = blockIdx.x;
    const int h   = blockIdx.y;
    const int tid = threadIdx.x;
    const int d0 = h * 154;
    const int d1 = (h == 0) ? 154 : NN;
    const f16* xlb = xl + (size_t)b * NN * UP;
    const f16* xrb = xr + (size_t)b * NN * UP;
    f16* stb = stg + (size_t)b * NN * UP;

    if (tid < UP) att_s[tid] = (tid < UU) ? (f16)att[tid] : (f16)0.f;
    for (int c = tid; c < NN * UP / 8; c += GT)
        *(f16x8*)&xl_s[c * 8] = *(const f16x8*)&xlb[c * 8];

    int dlo = d0;
    while (dlo < d1) {
        int dhi = d1;
        const int base = offs[dlo];
        if (offs[d1] - base > HCAP) {
            int lo = dlo + 1, hi = d1;
            while (lo < hi) {
                const int mid = (lo + hi + 1) >> 1;
                if (offs[mid] - base <= HCAP) lo = mid; else hi = mid - 1;
            }
            dhi = lo;
        }
        const int e0 = base, e1 = offs[dhi];
        const int n  = e1 - e0;

        for (int q = tid; q < n; q += GT) ei_s[q] = (u16)eidx[e0 + q];
        __syncthreads();   // also covers xl_s staging on first iteration

        // ---- scores (xl from LDS; xr row from global, d-local) ----
        for (int i = tid; i < n; i += GT) {
            const int s = ei_s[i];
            const int d = ddst[e0 + i];
            const f16x8* a8 = (const f16x8*)&xl_s[s * UP];
            const f16x8* r8 = (const f16x8*)(xrb + (size_t)d * UP);
            float p0 = 0.f, p1 = 0.f;
            #pragma unroll 4
            for (int c = 0; c < 13; ++c) {
                const f16x8 x  = a8[c] + r8[c];
                const f16x8 xm = x * (f16)0.2f;
                const f16x8 y  = __builtin_elementwise_max(x, xm);  // leaky
                const f16x2* y2  = (const f16x2*)&y;
                const f16x2* at2 = (const f16x2*)&att_s[c * 8];
#if __has_builtin(__builtin_amdgcn_fdot2)
                p0 = __builtin_amdgcn_fdot2(y2[0], at2[0], p0, false);
                p1 = __builtin_amdgcn_fdot2(y2[1], at2[1], p1, false);
                p0 = __builtin_amdgcn_fdot2(y2[2], at2[2], p0, false);
                p1 = __builtin_amdgcn_fdot2(y2[3], at2[3], p1, false);
#else
                #pragma unroll
                for (int q = 0; q < 4; ++q) {
                    p0 += (float)y2[q][0] * (float)at2[q][0];
                    p1 += (float)y2[q][1] * (float)at2[q][1];
                }
#endif
            }
            sc_s[i] = p0 + p1;
        }
        __syncthreads();

        // ---- per-dst softmax stats, alpha in-place ----
        {
            const int t = dlo + tid;
            if (t < dhi) {
                const int f0 = offs[t] - e0, f1 = offs[t + 1] - e0;
                float mx = -1e30f;
                for (int e = f0; e < f1; ++e) mx = fmaxf(mx, sc_s[e]);
                float dn = 0.f;
                for (int e = f0; e < f1; ++e) {
                    const float ex = __expf(sc_s[e] - mx);
                    sc_s[e] = ex;
                    dn += ex;
                }
                const float inv = 1.f / dn;
                for (int e = f0; e < f1; ++e) sc_s[e] *= inv;
            }
        }
        __syncthreads();

        // ---- aggregate -> st (LDS-only per-edge chain) ----
        {
            const int g   = tid >> 4;
            const int sub = tid & 15;
            const bool fa = (sub < 13);
            float bias_r[8];
            #pragma unroll
            for (int k = 0; k < 8; ++k) {
                const int f = sub * 8 + k;
                bias_r[k] = (fa && f < UU) ? (gb[f] + bgc[f]) : 0.f;
            }
            for (int d = dlo + g; d < dhi; d += NGRP) {
                const int f0 = offs[d] - e0, f1 = offs[d + 1] - e0;
                float acc[8] = {0.f, 0.f, 0.f, 0.f, 0.f, 0.f, 0.f, 0.f};
                for (int e = f0; e < f1; ++e) {
                    const float alpha = sc_s[e];         // LDS broadcast
                    const int s = ei_s[e];               // LDS broadcast
                    if (fa) {
                        const f16x8 m = *(const f16x8*)&xl_s[s * UP + sub * 8];
                        #pragma unroll
                        for (int k = 0; k < 8; ++k) acc[k] += alpha * (float)m[k];
                    }
                }
                if (fa) {
                    f16x8 o;
                    #pragma unroll
                    for (int k = 0; k < 8; ++k) o[k] = (f16)(acc[k] + bias_r[k]);
                    *(f16x8*)(stb + (size_t)d * UP + sub * 8) = o;
                }
            }
        }
        dlo = dhi;
        __syncthreads();   // protect ei_s/sc_s before next chunk restage
    }
}

// ---------------------------------------------------------------------------
// K2: GRU, barrier-free. 64 rows/block, 256 threads (4 waves); wave w owns
// rows [b*64 + w*16, +16). st staged once into wave-local LDS; r-gate -> rst
// LDS tile (+inp cols); u-gate in regs; rst re-read as A-frags (same-wave DS
// order); final -> out. launch_bounds(256,6): LDS cap is 6 blocks/CU; pin
// the VGPR budget to 85 so residency reaches the LDS cap (was reg-capped 4).
// ---------------------------------------------------------------------------
__global__ __launch_bounds__(256, 6)
void gru3_k(const f16* __restrict__ st, const float* __restrict__ inp,
            const f16* __restrict__ Wp2 /* unit 2 base */,
            const float* __restrict__ bg1, const float* __restrict__ bg2,
            float* __restrict__ out, int M)
{
    __shared__ f16 st_s[64 * UP];    // 13312 B
    __shared__ f16 rst_s[64 * UP];   // 13312 B

    const int tid = threadIdx.x;
    const int w = tid >> 6, l = tid & 63, lr = l & 15, lk = l >> 4;
    const int rb = blockIdx.x * 64 + w * 16;
    const int lbase = w * 16;

    // ---- stage wave-owned st rows -> LDS (same-wave DS order) ----
    #pragma unroll
    for (int p = 0; p < 4; ++p) {
        const int idx = p * 64 + l;
        const int row = idx >> 4, ch = idx & 15;
        if (ch < 13) {
            int gr = rb + row; if (gr >= M) gr = M - 1;
            *(f16x8*)&st_s[(lbase + row) * UP + ch * 8] =
                *(const f16x8*)(st + (size_t)gr * UP + ch * 8);
        }
    }

    // ---- A fragments from st_s + inp ----
    int crow = rb + lr; if (crow >= M) crow = M - 1;
    const f16* bh = &st_s[(lbase + lr) * UP];
    f16x8 af[4];
    #pragma unroll
    for (int s = 0; s < 3; ++s)
        af[s] = *(const f16x8*)(bh + (s * 4 + lk) * 8);
    {
        f16x8 v = (f16x8)(f16)0.f;
        if (lk == 0) {
            v = *(const f16x8*)(bh + 96);
            v[4] = (f16)inp[(size_t)crow * DD + 0];
            v[5] = (f16)inp[(size_t)crow * DD + 1];
            v[6] = (f16)inp[(size_t)crow * DD + 2];
            v[7] = (f16)0.f;
        }
        af[3] = v;
    }

    f32x4 acc[7];

    // ---- r-gate: rst = sigmoid(acc + bg1[col]) * st -> LDS ----
    z7(acc);
    mma_unit_nb(af, Wp2, l, acc);
    #pragma unroll
    for (int j = 0; j < 7; ++j) {
        const int col = j * 16 + lr;
        if (col >= UU) continue;
        const float bR = bg1[col];
        #pragma unroll
        for (int r = 0; r < 4; ++r) {
            const int grow = rb + lk * 4 + r;
            const int lrow = lbase + lk * 4 + r;
            if (grow < M) {
                const float stv = (float)st_s[lrow * UP + col];
                const float sg = fast_sigmoid(acc[j][r] + bR);
                rst_s[lrow * UP + col] = (f16)(sg * stv);
            }
        }
    }
    if (l < 16) {
        const int grow2 = rb + l;
        const int lrow2 = lbase + l;
        if (grow2 < M) {
            rst_s[lrow2 * UP + 100] = (f16)inp[(size_t)grow2 * DD + 0];
            rst_s[lrow2 * UP + 101] = (f16)inp[(size_t)grow2 * DD + 1];
            rst_s[lrow2 * UP + 102] = (f16)inp[(size_t)grow2 * DD + 2];
            rst_s[lrow2 * UP + 103] = (f16)0.f;
        }
    }

    // ---- u-gate: u = sigmoid(acc + bg1[100+col]) in regs ----
    z7(acc);
    mma_unit_nb(af, Wp2 + UNIT_W, l, acc);
    f16x4 uh[7];
    #pragma unroll
    for (int j = 0; j < 7; ++j) {
        const int col = j * 16 + lr;
        const float bU = (col < UU) ? bg1[UU + col] : 0.f;
        #pragma unroll
        for (int r = 0; r < 4; ++r)
            uh[j][r] = (f16)fast_sigmoid(acc[j][r] + bU);
    }

    // ---- rst A-frags from LDS (same-wave write->read, DS in-order) ----
    f16x8 af2[4];
    #pragma unroll
    for (int s = 0; s < 3; ++s)
        af2[s] = *(const f16x8*)&rst_s[(lbase + lr) * UP + (s * 4 + lk) * 8];
    af2[3] = (lk == 0) ? *(const f16x8*)&rst_s[(lbase + lr) * UP + 96]
                       : (f16x8)(f16)0.f;

    // ---- candidate + final output ----
    z7(acc);
    mma_unit_nb(af2, Wp2 + 2 * UNIT_W, l, acc);
    #pragma unroll
    for (int j = 0; j < 7; ++j) {
        const int col = j * 16 + lr;
        if (col >= UU) continue;
        const float bC = bg2[col];
        #pragma unroll
        for (int r = 0; r < 4; ++r) {
            const int grow = rb + lk * 4 + r;
            const int lrow = lbase + lk * 4 + r;
            if (grow < M) {
                const float c = fast_tanh(acc[j][r] + bC);
                const float u = (float)uh[j][r];
                const float stv = (float)st_s[lrow * UP + col];
                out[(size_t)grow * UU + col] = u * stv + (1.f - u) * c;
            }
        }
    }
}

// ---------------------------------------------------------------------------
extern "C" void kernel_launch(void* const* d_in, const int* in_sizes, int n_in,
                              void* d_out, int out_size, void* d_ws, size_t ws_size,
                              hipStream_t stream)
{
    const float* inputs   = (const float*)d_in[0];
    const float* state    = (const float*)d_in[1];
    const int*   src      = (const int*)  d_in[2];
    const int*   dst      = (const int*)  d_in[3];
    const float* Wl       = (const float*)d_in[4];
    const float* Wr       = (const float*)d_in[5];
    const float* att      = (const float*)d_in[6];
    const float* gat_bias = (const float*)d_in[7];
    const float* bias_gc  = (const float*)d_in[8];
    const float* Wg1      = (const float*)d_in[9];
    const float* bg1      = (const float*)d_in[10];
    const float* Wg2      = (const float*)d_in[11];
    const float* bg2      = (const float*)d_in[12];

    const int E = in_sizes[2];
    const int B = in_sizes[1] / (NN * UU);
    const int M = B * NN;
    const int Etot = E + NN;

    char* ws = (char*)d_ws;
    f16* Wp   = (f16*)ws;
    int* offs = (int*)(ws + 5 * UNIT_W * sizeof(f16));
    int* eidx = offs + (NN + 1);
    int* ddst = eidx + (Etot + 64);
    f16* xl_h = (f16*)(ws + (256 << 10));
    f16* xr_h = xl_h + (size_t)M * UP;
    f16* st_h = xr_h + (size_t)M * UP;
    float* out = (float*)d_out;

    // prep: weight pack + CSR count in one launch
    prep_k<<<PACK_BLOCKS + NN, 256, 0, stream>>>(Wl, Wr, Wg1, Wg2, Wp,
                                                 dst, E, offs);
    csr_scan_k<<<1, 512, 0, stream>>>(offs);
    csr_fill_k<<<NN, 64, 0, stream>>>(src, dst, E, offs, eidx, ddst);

    // K0: xl/xr GEMM (high occupancy, barrier-free) -> HBM
    gemm_xlxr_k<<<(M + 63) / 64, 256, 0, stream>>>(state, inputs, Wp,
                                                   xl_h, xr_h, M);

    // K1: GAT P2-P4, 2 blocks/sample (dst halves), 1024 thr, 2 blocks/CU -> st
    gat2h_k<<<dim3(B, 2), GT, 0, stream>>>(xl_h, xr_h, offs, eidx, ddst,
                                           att, gat_bias, bias_gc, st_h);

    // K2: GRU (barrier-free, fast activations, 6 blocks/CU) -> out
    gru3_k<<<(M + 63) / 64, 256, 0, stream>>>(st_h, inputs,
        Wp + 2 * (size_t)UNIT_W, bg1, bg2, out, M);
}

// Round 24
// 133.970 us; speedup vs baseline: 1.1093x; 1.1093x over previous
//
#include <hip/hip_runtime.h>
#include <math.h>

#define NN 307
#define UU 100
#define DD 3
#define UP 104          // padded f16 activation row stride (208 B, 16B-aligned)
#define UNIT_W 14336    // f16 elements per packed weight unit (4*7*64*8 = 112x128)
#define HCAP 2560       // per-chunk edge capacity in gat2h (half-sample slice)
#define GT 1024         // gat2h_k block size (16 waves; VGPR 32 fits 64 budget)
#define NGRP (GT / 16)
#define PACK_BLOCKS 280 // 280*256 = 71680 = 5*UNIT_W exact

typedef _Float16 f16;
typedef f16  f16x2 __attribute__((ext_vector_type(2)));
typedef f16  f16x4 __attribute__((ext_vector_type(4)));
typedef f16  f16x8 __attribute__((ext_vector_type(8)));
typedef float f32x4 __attribute__((ext_vector_type(4)));
typedef unsigned short u16;

// ---------------------------------------------------------------------------
// prep_k: merged pack_w (blocks [0,280)) + csr_count (blocks [280,587)).
// Count written RAW to cnt[] (scan happens in mid_k's fill blocks).
// ---------------------------------------------------------------------------
__global__ __launch_bounds__(256)
void prep_k(const float* __restrict__ Wl, const float* __restrict__ Wr,
            const float* __restrict__ Wg1, const float* __restrict__ Wg2,
            f16* __restrict__ Wp,
            const int* __restrict__ dst, int E, int* cnt)
{
    if (blockIdx.x < PACK_BLOCKS) {
        const int idx = blockIdx.x * 256 + threadIdx.x;
        const int u   = idx / UNIT_W;
        const int rem = idx - u * UNIT_W;
        const int e   = rem & 7;
        const int l   = (rem >> 3) & 63;
        const int sj  = rem >> 9;
        const int s   = sj / 7, j = sj - 7 * s;
        const int col = j * 16 + (l & 15);
        const int k   = (s * 4 + (l >> 4)) * 8 + e;
        float v = 0.f;
        if (col < UU && k < UU + DD) {
            if (u == 0)      v = Wl[k * UU + col];
            else if (u == 1) v = Wr[k * UU + col];
            else {
                const int kk = (k < UU) ? (k + DD) : (k - UU);
                if (u == 2)      v = Wg1[kk * (2 * UU) + col];
                else if (u == 3) v = Wg1[kk * (2 * UU) + UU + col];
                else             v = Wg2[kk * UU + col];
            }
        }
        Wp[idx] = (f16)v;
    } else {
        const int d = blockIdx.x - PACK_BLOCKS;     // 0..NN-1
        if (threadIdx.x >= 64) return;              // 1 wave does the count
        const int lane = threadIdx.x;
        const int Etot = E + NN;
        int c = 0;
        for (int base = 0; base < Etot; base += 64) {
            const int e = base + lane;
            if (e < Etot) {
                const int de = (e < E) ? dst[e] : (e - E);
                c += (de == d) ? 1 : 0;
            }
        }
        #pragma unroll
        for (int m = 1; m < 64; m <<= 1) c += __shfl_xor(c, m, 64);
        if (lane == 0) cnt[d] = c;
    }
}

// ---------------------------------------------------------------------------
// MFMA helper, barrier-free (global W loads must pipeline — r15/r18 lesson).
// ---------------------------------------------------------------------------
__device__ __forceinline__ void mma_unit_nb(const f16x8 (&af)[4],
                                            const f16* __restrict__ Wu,
                                            int l, f32x4 (&acc)[7])
{
    #pragma unroll
    for (int s = 0; s < 4; ++s)
        #pragma unroll
        for (int j = 0; j < 7; ++j) {
            const f16x8 bv = *(const f16x8*)(Wu + (((s * 7 + j) * 64 + l) << 3));
            acc[j] = __builtin_amdgcn_mfma_f32_16x16x32_f16(af[s], bv, acc[j], 0, 0, 0);
        }
}

__device__ __forceinline__ void z7(f32x4 (&acc)[7])
{
    #pragma unroll
    for (int j = 0; j < 7; ++j) acc[j] = (f32x4)0.f;
}

__device__ __forceinline__ float fast_sigmoid(float x)
{
    return __fdividef(1.f, 1.f + __expf(-x));
}

__device__ __forceinline__ float fast_tanh(float x)
{
    return 1.f - __fdividef(2.f, __expf(2.f * x) + 1.f);
}

// ---------------------------------------------------------------------------
// mid_k: merged CSR-fill (blocks [0,NN)) + xl/xr GEMM (blocks [NN, NN+mb)).
// Both depend only on prep_k; merging saves 2 launch gaps (fill blocks also
// compute their own prefix from cnt[] — replaces csr_scan_k).
// ---------------------------------------------------------------------------
__global__ __launch_bounds__(256, 4)
void mid_k(const int* __restrict__ src, const int* __restrict__ dst, int E,
           const int* __restrict__ cnt, int* __restrict__ offs,
           int* __restrict__ eidx, int* __restrict__ ddst,
           const float* __restrict__ state, const float* __restrict__ inp,
           const f16* __restrict__ Wp,
           f16* __restrict__ xl, f16* __restrict__ xr, int M)
{
    if (blockIdx.x < NN) {
        // ---- CSR fill for dst node d, with self-computed prefix base ----
        const int d = blockIdx.x;
        if (threadIdx.x >= 64) return;
        const int lane = threadIdx.x;
        int base = 0;
        for (int i = lane; i < d; i += 64) base += cnt[i];
        #pragma unroll
        for (int m = 1; m < 64; m <<= 1) base += __shfl_xor(base, m, 64);
        if (lane == 0) {
            offs[d + 1] = base + cnt[d];
            if (d == 0) offs[0] = 0;
        }
        const int Etot = E + NN;
        int w = base;
        for (int eb = 0; eb < Etot; eb += 64) {
            const int e = eb + lane;
            bool match = false;
            int se = 0;
            if (e < Etot) {
                const int de = (e < E) ? dst[e] : (e - E);
                se           = (e < E) ? src[e] : (e - E);
                match = (de == d);
            }
            const unsigned long long mask = __ballot(match);
            if (match) {
                const int pos = w + __popcll(mask & ((1ULL << lane) - 1ULL));
                eidx[pos] = se;
                ddst[pos] = d;
            }
            w += __popcll(mask);
        }
    } else {
        // ---- xl/xr GEMM (r19-validated body) ----
        const int tid = threadIdx.x;
        const int w = tid >> 6, l = tid & 63, lr = l & 15, lk = l >> 4;
        const int rb = (blockIdx.x - NN) * 64 + w * 16;
        int crow = rb + lr; if (crow >= M) crow = M - 1;
        const float* bf = state + (size_t)crow * UU;

        f16x8 af[4];
        #pragma unroll
        for (int s = 0; s < 3; ++s) {
            const int kb = s * 4 + lk;
            const float4 x0 = *(const float4*)(bf + kb * 8);
            const float4 x1 = *(const float4*)(bf + kb * 8 + 4);
            f16x8 v;
            v[0]=(f16)x0.x; v[1]=(f16)x0.y; v[2]=(f16)x0.z; v[3]=(f16)x0.w;
            v[4]=(f16)x1.x; v[5]=(f16)x1.y; v[6]=(f16)x1.z; v[7]=(f16)x1.w;
            af[s] = v;
        }
        {
            f16x8 v = (f16x8)(f16)0.f;
            if (lk == 0) {
                const float4 x0 = *(const float4*)(bf + 96);
                v[0]=(f16)x0.x; v[1]=(f16)x0.y; v[2]=(f16)x0.z; v[3]=(f16)x0.w;
                v[4] = (f16)inp[(size_t)crow * DD + 0];
                v[5] = (f16)inp[(size_t)crow * DD + 1];
                v[6] = (f16)inp[(size_t)crow * DD + 2];
                v[7] = (f16)0.f;
            }
            af[3] = v;
        }

        #pragma unroll
        for (int u = 0; u < 2; ++u) {
            f32x4 acc[7];
            z7(acc);
            mma_unit_nb(af, Wp + (size_t)u * UNIT_W, l, acc);
            f16* dstp = u ? xr : xl;
            #pragma unroll
            for (int j = 0; j < 7; ++j) {
                const int col = j * 16 + lr;
                if (col >= UU) continue;
                #pragma unroll
                for (int r = 0; r < 4; ++r) {
                    const int row = rb + lk * 4 + r;
                    if (row < M) dstp[(size_t)row * UP + col] = (f16)acc[j][r];
                }
            }
        }
    }
}

// ---------------------------------------------------------------------------
// K1: GAT P2-P4, half-sample blocks, 1024 threads (r20-validated: VGPR 32,
// 2 blocks/CU = 32 waves/CU). xr rows read from global (CSR d-locality).
// ---------------------------------------------------------------------------
__global__ __launch_bounds__(GT, 8)
void gat2h_k(const f16* __restrict__ xl, const f16* __restrict__ xr,
             const int* __restrict__ offs, const int* __restrict__ eidx,
             const int* __restrict__ ddst,
             const float* __restrict__ att, const float* __restrict__ gb,
             const float* __restrict__ bgc,
             f16* __restrict__ stg)
{
    __shared__ f16   xl_s[NN * UP];    // 63856 B
    __shared__ float sc_s[HCAP];       // 10240 B
    __shared__ u16   ei_s[HCAP];       // 5120 B
    __shared__ f16   att_s[UP];        // 208 B

    const int b   = blockIdx.x;
    const int h   = blockIdx.y;
    const int tid = threadIdx.x;
    const int d0 = h * 154;
    const int d1 = (h == 0) ? 154 : NN;
    const f16* xlb = xl + (size_t)b * NN * UP;
    const f16* xrb = xr + (size_t)b * NN * UP;
    f16* stb = stg + (size_t)b * NN * UP;

    if (tid < UP) att_s[tid] = (tid < UU) ? (f16)att[tid] : (f16)0.f;
    for (int c = tid; c < NN * UP / 8; c += GT)
        *(f16x8*)&xl_s[c * 8] = *(const f16x8*)&xlb[c * 8];

    int dlo = d0;
    while (dlo < d1) {
        int dhi = d1;
        const int base = offs[dlo];
        if (offs[d1] - base > HCAP) {
            int lo = dlo + 1, hi = d1;
            while (lo < hi) {
                const int mid = (lo + hi + 1) >> 1;
                if (offs[mid] - base <= HCAP) lo = mid; else hi = mid - 1;
            }
            dhi = lo;
        }
        const int e0 = base, e1 = offs[dhi];
        const int n  = e1 - e0;

        for (int q = tid; q < n; q += GT) ei_s[q] = (u16)eidx[e0 + q];
        __syncthreads();   // also covers xl_s staging on first iteration

        // ---- scores (xl from LDS; xr row from global, d-local) ----
        for (int i = tid; i < n; i += GT) {
            const int s = ei_s[i];
            const int d = ddst[e0 + i];
            const f16x8* a8 = (const f16x8*)&xl_s[s * UP];
            const f16x8* r8 = (const f16x8*)(xrb + (size_t)d * UP);
            float p0 = 0.f, p1 = 0.f;
            #pragma unroll 4
            for (int c = 0; c < 13; ++c) {
                const f16x8 x  = a8[c] + r8[c];
                const f16x8 xm = x * (f16)0.2f;
                const f16x8 y  = __builtin_elementwise_max(x, xm);  // leaky
                const f16x2* y2  = (const f16x2*)&y;
                const f16x2* at2 = (const f16x2*)&att_s[c * 8];
#if __has_builtin(__builtin_amdgcn_fdot2)
                p0 = __builtin_amdgcn_fdot2(y2[0], at2[0], p0, false);
                p1 = __builtin_amdgcn_fdot2(y2[1], at2[1], p1, false);
                p0 = __builtin_amdgcn_fdot2(y2[2], at2[2], p0, false);
                p1 = __builtin_amdgcn_fdot2(y2[3], at2[3], p1, false);
#else
                #pragma unroll
                for (int q = 0; q < 4; ++q) {
                    p0 += (float)y2[q][0] * (float)at2[q][0];
                    p1 += (float)y2[q][1] * (float)at2[q][1];
                }
#endif
            }
            sc_s[i] = p0 + p1;
        }
        __syncthreads();

        // ---- per-dst softmax stats, alpha in-place ----
        {
            const int t = dlo + tid;
            if (t < dhi) {
                const int f0 = offs[t] - e0, f1 = offs[t + 1] - e0;
                float mx = -1e30f;
                for (int e = f0; e < f1; ++e) mx = fmaxf(mx, sc_s[e]);
                float dn = 0.f;
                for (int e = f0; e < f1; ++e) {
                    const float ex = __expf(sc_s[e] - mx);
                    sc_s[e] = ex;
                    dn += ex;
                }
                const float inv = 1.f / dn;
                for (int e = f0; e < f1; ++e) sc_s[e] *= inv;
            }
        }
        __syncthreads();

        // ---- aggregate -> st (LDS-only per-edge chain) ----
        {
            const int g   = tid >> 4;
            const int sub = tid & 15;
            const bool fa = (sub < 13);
            float bias_r[8];
            #pragma unroll
            for (int k = 0; k < 8; ++k) {
                const int f = sub * 8 + k;
                bias_r[k] = (fa && f < UU) ? (gb[f] + bgc[f]) : 0.f;
            }
            for (int d = dlo + g; d < dhi; d += NGRP) {
                const int f0 = offs[d] - e0, f1 = offs[d + 1] - e0;
                float acc[8] = {0.f, 0.f, 0.f, 0.f, 0.f, 0.f, 0.f, 0.f};
                for (int e = f0; e < f1; ++e) {
                    const float alpha = sc_s[e];         // LDS broadcast
                    const int s = ei_s[e];               // LDS broadcast
                    if (fa) {
                        const f16x8 m = *(const f16x8*)&xl_s[s * UP + sub * 8];
                        #pragma unroll
                        for (int k = 0; k < 8; ++k) acc[k] += alpha * (float)m[k];
                    }
                }
                if (fa) {
                    f16x8 o;
                    #pragma unroll
                    for (int k = 0; k < 8; ++k) o[k] = (f16)(acc[k] + bias_r[k]);
                    *(f16x8*)(stb + (size_t)d * UP + sub * 8) = o;
                }
            }
        }
        dlo = dhi;
        __syncthreads();   // protect ei_s/sc_s before next chunk restage
    }
}

// ---------------------------------------------------------------------------
// K2: GRU, barrier-free (r23 config: (256,6), VGPR 40, no spill).
// ---------------------------------------------------------------------------
__global__ __launch_bounds__(256, 6)
void gru3_k(const f16* __restrict__ st, const float* __restrict__ inp,
            const f16* __restrict__ Wp2 /* unit 2 base */,
            const float* __restrict__ bg1, const float* __restrict__ bg2,
            float* __restrict__ out, int M)
{
    __shared__ f16 st_s[64 * UP];    // 13312 B
    __shared__ f16 rst_s[64 * UP];   // 13312 B

    const int tid = threadIdx.x;
    const int w = tid >> 6, l = tid & 63, lr = l & 15, lk = l >> 4;
    const int rb = blockIdx.x * 64 + w * 16;
    const int lbase = w * 16;

    // ---- stage wave-owned st rows -> LDS (same-wave DS order) ----
    #pragma unroll
    for (int p = 0; p < 4; ++p) {
        const int idx = p * 64 + l;
        const int row = idx >> 4, ch = idx & 15;
        if (ch < 13) {
            int gr = rb + row; if (gr >= M) gr = M - 1;
            *(f16x8*)&st_s[(lbase + row) * UP + ch * 8] =
                *(const f16x8*)(st + (size_t)gr * UP + ch * 8);
        }
    }

    // ---- A fragments from st_s + inp ----
    int crow = rb + lr; if (crow >= M) crow = M - 1;
    const f16* bh = &st_s[(lbase + lr) * UP];
    f16x8 af[4];
    #pragma unroll
    for (int s = 0; s < 3; ++s)
        af[s] = *(const f16x8*)(bh + (s * 4 + lk) * 8);
    {
        f16x8 v = (f16x8)(f16)0.f;
        if (lk == 0) {
            v = *(const f16x8*)(bh + 96);
            v[4] = (f16)inp[(size_t)crow * DD + 0];
            v[5] = (f16)inp[(size_t)crow * DD + 1];
            v[6] = (f16)inp[(size_t)crow * DD + 2];
            v[7] = (f16)0.f;
        }
        af[3] = v;
    }

    f32x4 acc[7];

    // ---- r-gate: rst = sigmoid(acc + bg1[col]) * st -> LDS ----
    z7(acc);
    mma_unit_nb(af, Wp2, l, acc);
    #pragma unroll
    for (int j = 0; j < 7; ++j) {
        const int col = j * 16 + lr;
        if (col >= UU) continue;
        const float bR = bg1[col];
        #pragma unroll
        for (int r = 0; r < 4; ++r) {
            const int grow = rb + lk * 4 + r;
            const int lrow = lbase + lk * 4 + r;
            if (grow < M) {
                const float stv = (float)st_s[lrow * UP + col];
                const float sg = fast_sigmoid(acc[j][r] + bR);
                rst_s[lrow * UP + col] = (f16)(sg * stv);
            }
        }
    }
    if (l < 16) {
        const int grow2 = rb + l;
        const int lrow2 = lbase + l;
        if (grow2 < M) {
            rst_s[lrow2 * UP + 100] = (f16)inp[(size_t)grow2 * DD + 0];
            rst_s[lrow2 * UP + 101] = (f16)inp[(size_t)grow2 * DD + 1];
            rst_s[lrow2 * UP + 102] = (f16)inp[(size_t)grow2 * DD + 2];
            rst_s[lrow2 * UP + 103] = (f16)0.f;
        }
    }

    // ---- u-gate: u = sigmoid(acc + bg1[100+col]) in regs ----
    z7(acc);
    mma_unit_nb(af, Wp2 + UNIT_W, l, acc);
    f16x4 uh[7];
    #pragma unroll
    for (int j = 0; j < 7; ++j) {
        const int col = j * 16 + lr;
        const float bU = (col < UU) ? bg1[UU + col] : 0.f;
        #pragma unroll
        for (int r = 0; r < 4; ++r)
            uh[j][r] = (f16)fast_sigmoid(acc[j][r] + bU);
    }

    // ---- rst A-frags from LDS (same-wave write->read, DS in-order) ----
    f16x8 af2[4];
    #pragma unroll
    for (int s = 0; s < 3; ++s)
        af2[s] = *(const f16x8*)&rst_s[(lbase + lr) * UP + (s * 4 + lk) * 8];
    af2[3] = (lk == 0) ? *(const f16x8*)&rst_s[(lbase + lr) * UP + 96]
                       : (f16x8)(f16)0.f;

    // ---- candidate + final output ----
    z7(acc);
    mma_unit_nb(af2, Wp2 + 2 * UNIT_W, l, acc);
    #pragma unroll
    for (int j = 0; j < 7; ++j) {
        const int col = j * 16 + lr;
        if (col >= UU) continue;
        const float bC = bg2[col];
        #pragma unroll
        for (int r = 0; r < 4; ++r) {
            const int grow = rb + lk * 4 + r;
            const int lrow = lbase + lk * 4 + r;
            if (grow < M) {
                const float c = fast_tanh(acc[j][r] + bC);
                const float u = (float)uh[j][r];
                const float stv = (float)st_s[lrow * UP + col];
                out[(size_t)grow * UU + col] = u * stv + (1.f - u) * c;
            }
        }
    }
}

// ---------------------------------------------------------------------------
extern "C" void kernel_launch(void* const* d_in, const int* in_sizes, int n_in,
                              void* d_out, int out_size, void* d_ws, size_t ws_size,
                              hipStream_t stream)
{
    const float* inputs   = (const float*)d_in[0];
    const float* state    = (const float*)d_in[1];
    const int*   src      = (const int*)  d_in[2];
    const int*   dst      = (const int*)  d_in[3];
    const float* Wl       = (const float*)d_in[4];
    const float* Wr       = (const float*)d_in[5];
    const float* att      = (const float*)d_in[6];
    const float* gat_bias = (const float*)d_in[7];
    const float* bias_gc  = (const float*)d_in[8];
    const float* Wg1      = (const float*)d_in[9];
    const float* bg1      = (const float*)d_in[10];
    const float* Wg2      = (const float*)d_in[11];
    const float* bg2      = (const float*)d_in[12];

    const int E = in_sizes[2];
    const int B = in_sizes[1] / (NN * UU);
    const int M = B * NN;
    const int Etot = E + NN;
    const int mb = (M + 63) / 64;

    char* ws = (char*)d_ws;
    f16* Wp   = (f16*)ws;
    int* offs = (int*)(ws + 5 * UNIT_W * sizeof(f16));
    int* cnt  = offs + (NN + 1);
    int* eidx = cnt + NN;
    int* ddst = eidx + (Etot + 64);
    f16* xl_h = (f16*)(ws + (256 << 10));
    f16* xr_h = xl_h + (size_t)M * UP;
    f16* st_h = xr_h + (size_t)M * UP;
    float* out = (float*)d_out;

    // L1: weight pack + CSR count (raw)
    prep_k<<<PACK_BLOCKS + NN, 256, 0, stream>>>(Wl, Wr, Wg1, Wg2, Wp,
                                                 dst, E, cnt);
    // L2: CSR fill (self-scanned) + xl/xr GEMM
    mid_k<<<NN + mb, 256, 0, stream>>>(src, dst, E, cnt, offs, eidx, ddst,
                                       state, inputs, Wp, xl_h, xr_h, M);
    // L3: GAT P2-P4 -> st
    gat2h_k<<<dim3(B, 2), GT, 0, stream>>>(xl_h, xr_h, offs, eidx, ddst,
                                           att, gat_bias, bias_gc, st_h);
    // L4: GRU -> out
    gru3_k<<<mb, 256, 0, stream>>>(st_h, inputs,
        Wp + 2 * (size_t)UNIT_W, bg1, bg2, out, M);
}

// Round 25
// 133.823 us; speedup vs baseline: 1.1105x; 1.0011x over previous
//
#include <hip/hip_runtime.h>
#include <math.h>

#define NN 307
#define UU 100
#define DD 3
#define UP 104          // padded f16 activation row stride (208 B, 16B-aligned)
#define UNIT_W 14336    // f16 elements per packed weight unit (4*7*64*8 = 112x128)
#define HCAP 2560       // per-chunk edge capacity in gat2h (half-sample slice)
#define GT 1024         // gat2h_k block size (16 waves; VGPR 32 fits 64 budget)
#define NGRP (GT / 16)
#define PACK_BLOCKS 280 // 280*256 = 71680 = 5*UNIT_W exact

typedef _Float16 f16;
typedef f16  f16x2 __attribute__((ext_vector_type(2)));
typedef f16  f16x4 __attribute__((ext_vector_type(4)));
typedef f16  f16x8 __attribute__((ext_vector_type(8)));
typedef float f32x4 __attribute__((ext_vector_type(4)));
typedef unsigned short u16;

// ---------------------------------------------------------------------------
// prep_k: merged pack_w (blocks [0,280)) + csr_count (blocks [280,587)).
// Count written RAW to cnt[] (scan happens in mid_k's fill blocks).
// ---------------------------------------------------------------------------
__global__ __launch_bounds__(256)
void prep_k(const float* __restrict__ Wl, const float* __restrict__ Wr,
            const float* __restrict__ Wg1, const float* __restrict__ Wg2,
            f16* __restrict__ Wp,
            const int* __restrict__ dst, int E, int* cnt)
{
    if (blockIdx.x < PACK_BLOCKS) {
        const int idx = blockIdx.x * 256 + threadIdx.x;
        const int u   = idx / UNIT_W;
        const int rem = idx - u * UNIT_W;
        const int e   = rem & 7;
        const int l   = (rem >> 3) & 63;
        const int sj  = rem >> 9;
        const int s   = sj / 7, j = sj - 7 * s;
        const int col = j * 16 + (l & 15);
        const int k   = (s * 4 + (l >> 4)) * 8 + e;
        float v = 0.f;
        if (col < UU && k < UU + DD) {
            if (u == 0)      v = Wl[k * UU + col];
            else if (u == 1) v = Wr[k * UU + col];
            else {
                const int kk = (k < UU) ? (k + DD) : (k - UU);
                if (u == 2)      v = Wg1[kk * (2 * UU) + col];
                else if (u == 3) v = Wg1[kk * (2 * UU) + UU + col];
                else             v = Wg2[kk * UU + col];
            }
        }
        Wp[idx] = (f16)v;
    } else {
        const int d = blockIdx.x - PACK_BLOCKS;     // 0..NN-1
        if (threadIdx.x >= 64) return;              // 1 wave does the count
        const int lane = threadIdx.x;
        const int Etot = E + NN;
        int c = 0;
        for (int base = 0; base < Etot; base += 64) {
            const int e = base + lane;
            if (e < Etot) {
                const int de = (e < E) ? dst[e] : (e - E);
                c += (de == d) ? 1 : 0;
            }
        }
        #pragma unroll
        for (int m = 1; m < 64; m <<= 1) c += __shfl_xor(c, m, 64);
        if (lane == 0) cnt[d] = c;
    }
}

// ---------------------------------------------------------------------------
// MFMA helper, barrier-free (global W loads must pipeline — r15/r18 lesson).
// ---------------------------------------------------------------------------
__device__ __forceinline__ void mma_unit_nb(const f16x8 (&af)[4],
                                            const f16* __restrict__ Wu,
                                            int l, f32x4 (&acc)[7])
{
    #pragma unroll
    for (int s = 0; s < 4; ++s)
        #pragma unroll
        for (int j = 0; j < 7; ++j) {
            const f16x8 bv = *(const f16x8*)(Wu + (((s * 7 + j) * 64 + l) << 3));
            acc[j] = __builtin_amdgcn_mfma_f32_16x16x32_f16(af[s], bv, acc[j], 0, 0, 0);
        }
}

// Dual-unit interleave: both units consume the same af; 14 independent
// accumulation chains and one merged W load stream (gru3 r/u gates).
__device__ __forceinline__ void mma_unit2_nb(const f16x8 (&af)[4],
                                             const f16* __restrict__ Wu0,
                                             const f16* __restrict__ Wu1,
                                             int l, f32x4 (&accA)[7],
                                             f32x4 (&accB)[7])
{
    #pragma unroll
    for (int s = 0; s < 4; ++s)
        #pragma unroll
        for (int j = 0; j < 7; ++j) {
            const int off = ((s * 7 + j) * 64 + l) << 3;
            const f16x8 bvA = *(const f16x8*)(Wu0 + off);
            const f16x8 bvB = *(const f16x8*)(Wu1 + off);
            accA[j] = __builtin_amdgcn_mfma_f32_16x16x32_f16(af[s], bvA, accA[j], 0, 0, 0);
            accB[j] = __builtin_amdgcn_mfma_f32_16x16x32_f16(af[s], bvB, accB[j], 0, 0, 0);
        }
}

__device__ __forceinline__ void z7(f32x4 (&acc)[7])
{
    #pragma unroll
    for (int j = 0; j < 7; ++j) acc[j] = (f32x4)0.f;
}

__device__ __forceinline__ float fast_sigmoid(float x)
{
    return __fdividef(1.f, 1.f + __expf(-x));
}

__device__ __forceinline__ float fast_tanh(float x)
{
    return 1.f - __fdividef(2.f, __expf(2.f * x) + 1.f);
}

// ---------------------------------------------------------------------------
// mid_k: merged CSR-fill (blocks [0,NN)) + xl/xr GEMM (blocks [NN, NN+mb)).
// ---------------------------------------------------------------------------
__global__ __launch_bounds__(256, 4)
void mid_k(const int* __restrict__ src, const int* __restrict__ dst, int E,
           const int* __restrict__ cnt, int* __restrict__ offs,
           int* __restrict__ eidx, int* __restrict__ ddst,
           const float* __restrict__ state, const float* __restrict__ inp,
           const f16* __restrict__ Wp,
           f16* __restrict__ xl, f16* __restrict__ xr, int M)
{
    if (blockIdx.x < NN) {
        // ---- CSR fill for dst node d, with self-computed prefix base ----
        const int d = blockIdx.x;
        if (threadIdx.x >= 64) return;
        const int lane = threadIdx.x;
        int base = 0;
        for (int i = lane; i < d; i += 64) base += cnt[i];
        #pragma unroll
        for (int m = 1; m < 64; m <<= 1) base += __shfl_xor(base, m, 64);
        if (lane == 0) {
            offs[d + 1] = base + cnt[d];
            if (d == 0) offs[0] = 0;
        }
        const int Etot = E + NN;
        int w = base;
        for (int eb = 0; eb < Etot; eb += 64) {
            const int e = eb + lane;
            bool match = false;
            int se = 0;
            if (e < Etot) {
                const int de = (e < E) ? dst[e] : (e - E);
                se           = (e < E) ? src[e] : (e - E);
                match = (de == d);
            }
            const unsigned long long mask = __ballot(match);
            if (match) {
                const int pos = w + __popcll(mask & ((1ULL << lane) - 1ULL));
                eidx[pos] = se;
                ddst[pos] = d;
            }
            w += __popcll(mask);
        }
    } else {
        // ---- xl/xr GEMM (r19-validated body) ----
        const int tid = threadIdx.x;
        const int w = tid >> 6, l = tid & 63, lr = l & 15, lk = l >> 4;
        const int rb = (blockIdx.x - NN) * 64 + w * 16;
        int crow = rb + lr; if (crow >= M) crow = M - 1;
        const float* bf = state + (size_t)crow * UU;

        f16x8 af[4];
        #pragma unroll
        for (int s = 0; s < 3; ++s) {
            const int kb = s * 4 + lk;
            const float4 x0 = *(const float4*)(bf + kb * 8);
            const float4 x1 = *(const float4*)(bf + kb * 8 + 4);
            f16x8 v;
            v[0]=(f16)x0.x; v[1]=(f16)x0.y; v[2]=(f16)x0.z; v[3]=(f16)x0.w;
            v[4]=(f16)x1.x; v[5]=(f16)x1.y; v[6]=(f16)x1.z; v[7]=(f16)x1.w;
            af[s] = v;
        }
        {
            f16x8 v = (f16x8)(f16)0.f;
            if (lk == 0) {
                const float4 x0 = *(const float4*)(bf + 96);
                v[0]=(f16)x0.x; v[1]=(f16)x0.y; v[2]=(f16)x0.z; v[3]=(f16)x0.w;
                v[4] = (f16)inp[(size_t)crow * DD + 0];
                v[5] = (f16)inp[(size_t)crow * DD + 1];
                v[6] = (f16)inp[(size_t)crow * DD + 2];
                v[7] = (f16)0.f;
            }
            af[3] = v;
        }

        #pragma unroll
        for (int u = 0; u < 2; ++u) {
            f32x4 acc[7];
            z7(acc);
            mma_unit_nb(af, Wp + (size_t)u * UNIT_W, l, acc);
            f16* dstp = u ? xr : xl;
            #pragma unroll
            for (int j = 0; j < 7; ++j) {
                const int col = j * 16 + lr;
                if (col >= UU) continue;
                #pragma unroll
                for (int r = 0; r < 4; ++r) {
                    const int row = rb + lk * 4 + r;
                    if (row < M) dstp[(size_t)row * UP + col] = (f16)acc[j][r];
                }
            }
        }
    }
}

// ---------------------------------------------------------------------------
// K1: GAT P2-P4, half-sample blocks, 1024 threads (r20-validated: VGPR 32,
// 2 blocks/CU = 32 waves/CU). xr rows read from global (CSR d-locality).
// ---------------------------------------------------------------------------
__global__ __launch_bounds__(GT, 8)
void gat2h_k(const f16* __restrict__ xl, const f16* __restrict__ xr,
             const int* __restrict__ offs, const int* __restrict__ eidx,
             const int* __restrict__ ddst,
             const float* __restrict__ att, const float* __restrict__ gb,
             const float* __restrict__ bgc,
             f16* __restrict__ stg)
{
    __shared__ f16   xl_s[NN * UP];    // 63856 B
    __shared__ float sc_s[HCAP];       // 10240 B
    __shared__ u16   ei_s[HCAP];       // 5120 B
    __shared__ f16   att_s[UP];        // 208 B

    const int b   = blockIdx.x;
    const int h   = blockIdx.y;
    const int tid = threadIdx.x;
    const int d0 = h * 154;
    const int d1 = (h == 0) ? 154 : NN;
    const f16* xlb = xl + (size_t)b * NN * UP;
    const f16* xrb = xr + (size_t)b * NN * UP;
    f16* stb = stg + (size_t)b * NN * UP;

    if (tid < UP) att_s[tid] = (tid < UU) ? (f16)att[tid] : (f16)0.f;
    for (int c = tid; c < NN * UP / 8; c += GT)
        *(f16x8*)&xl_s[c * 8] = *(const f16x8*)&xlb[c * 8];

    int dlo = d0;
    while (dlo < d1) {
        int dhi = d1;
        const int base = offs[dlo];
        if (offs[d1] - base > HCAP) {
            int lo = dlo + 1, hi = d1;
            while (lo < hi) {
                const int mid = (lo + hi + 1) >> 1;
                if (offs[mid] - base <= HCAP) lo = mid; else hi = mid - 1;
            }
            dhi = lo;
        }
        const int e0 = base, e1 = offs[dhi];
        const int n  = e1 - e0;

        for (int q = tid; q < n; q += GT) ei_s[q] = (u16)eidx[e0 + q];
        __syncthreads();   // also covers xl_s staging on first iteration

        // ---- scores (xl from LDS; xr row from global, d-local) ----
        for (int i = tid; i < n; i += GT) {
            const int s = ei_s[i];
            const int d = ddst[e0 + i];
            const f16x8* a8 = (const f16x8*)&xl_s[s * UP];
            const f16x8* r8 = (const f16x8*)(xrb + (size_t)d * UP);
            float p0 = 0.f, p1 = 0.f;
            #pragma unroll 4
            for (int c = 0; c < 13; ++c) {
                const f16x8 x  = a8[c] + r8[c];
                const f16x8 xm = x * (f16)0.2f;
                const f16x8 y  = __builtin_elementwise_max(x, xm);  // leaky
                const f16x2* y2  = (const f16x2*)&y;
                const f16x2* at2 = (const f16x2*)&att_s[c * 8];
#if __has_builtin(__builtin_amdgcn_fdot2)
                p0 = __builtin_amdgcn_fdot2(y2[0], at2[0], p0, false);
                p1 = __builtin_amdgcn_fdot2(y2[1], at2[1], p1, false);
                p0 = __builtin_amdgcn_fdot2(y2[2], at2[2], p0, false);
                p1 = __builtin_amdgcn_fdot2(y2[3], at2[3], p1, false);
#else
                #pragma unroll
                for (int q = 0; q < 4; ++q) {
                    p0 += (float)y2[q][0] * (float)at2[q][0];
                    p1 += (float)y2[q][1] * (float)at2[q][1];
                }
#endif
            }
            sc_s[i] = p0 + p1;
        }
        __syncthreads();

        // ---- per-dst softmax stats, alpha in-place ----
        {
            const int t = dlo + tid;
            if (t < dhi) {
                const int f0 = offs[t] - e0, f1 = offs[t + 1] - e0;
                float mx = -1e30f;
                for (int e = f0; e < f1; ++e) mx = fmaxf(mx, sc_s[e]);
                float dn = 0.f;
                for (int e = f0; e < f1; ++e) {
                    const float ex = __expf(sc_s[e] - mx);
                    sc_s[e] = ex;
                    dn += ex;
                }
                const float inv = 1.f / dn;
                for (int e = f0; e < f1; ++e) sc_s[e] *= inv;
            }
        }
        __syncthreads();

        // ---- aggregate -> st (LDS-only per-edge chain) ----
        {
            const int g   = tid >> 4;
            const int sub = tid & 15;
            const bool fa = (sub < 13);
            float bias_r[8];
            #pragma unroll
            for (int k = 0; k < 8; ++k) {
                const int f = sub * 8 + k;
                bias_r[k] = (fa && f < UU) ? (gb[f] + bgc[f]) : 0.f;
            }
            for (int d = dlo + g; d < dhi; d += NGRP) {
                const int f0 = offs[d] - e0, f1 = offs[d + 1] - e0;
                float acc[8] = {0.f, 0.f, 0.f, 0.f, 0.f, 0.f, 0.f, 0.f};
                for (int e = f0; e < f1; ++e) {
                    const float alpha = sc_s[e];         // LDS broadcast
                    const int s = ei_s[e];               // LDS broadcast
                    if (fa) {
                        const f16x8 m = *(const f16x8*)&xl_s[s * UP + sub * 8];
                        #pragma unroll
                        for (int k = 0; k < 8; ++k) acc[k] += alpha * (float)m[k];
                    }
                }
                if (fa) {
                    f16x8 o;
                    #pragma unroll
                    for (int k = 0; k < 8; ++k) o[k] = (f16)(acc[k] + bias_r[k]);
                    *(f16x8*)(stb + (size_t)d * UP + sub * 8) = o;
                }
            }
        }
        dlo = dhi;
        __syncthreads();   // protect ei_s/sc_s before next chunk restage
    }
}

// ---------------------------------------------------------------------------
// K2: GRU, barrier-free. 64 rows/block, 256 threads (4 waves); wave w owns
// rows [b*64 + w*16, +16). st staged into wave-local LDS; r/u gates computed
// with INTERLEAVED dual-unit MFMA (14 indep chains, one W stream) — halves
// the serial MFMA span of phase A; then rst re-read as A-frags; final -> out.
// (256,4): dual accumulators need the 128-reg budget.
// ---------------------------------------------------------------------------
__global__ __launch_bounds__(256, 4)
void gru3_k(const f16* __restrict__ st, const float* __restrict__ inp,
            const f16* __restrict__ Wp2 /* unit 2 base */,
            const float* __restrict__ bg1, const float* __restrict__ bg2,
            float* __restrict__ out, int M)
{
    __shared__ f16 st_s[64 * UP];    // 13312 B
    __shared__ f16 rst_s[64 * UP];   // 13312 B

    const int tid = threadIdx.x;
    const int w = tid >> 6, l = tid & 63, lr = l & 15, lk = l >> 4;
    const int rb = blockIdx.x * 64 + w * 16;
    const int lbase = w * 16;

    // ---- stage wave-owned st rows -> LDS (same-wave DS order) ----
    #pragma unroll
    for (int p = 0; p < 4; ++p) {
        const int idx = p * 64 + l;
        const int row = idx >> 4, ch = idx & 15;
        if (ch < 13) {
            int gr = rb + row; if (gr >= M) gr = M - 1;
            *(f16x8*)&st_s[(lbase + row) * UP + ch * 8] =
                *(const f16x8*)(st + (size_t)gr * UP + ch * 8);
        }
    }

    // ---- A fragments from st_s + inp ----
    int crow = rb + lr; if (crow >= M) crow = M - 1;
    const f16* bh = &st_s[(lbase + lr) * UP];
    f16x8 af[4];
    #pragma unroll
    for (int s = 0; s < 3; ++s)
        af[s] = *(const f16x8*)(bh + (s * 4 + lk) * 8);
    {
        f16x8 v = (f16x8)(f16)0.f;
        if (lk == 0) {
            v = *(const f16x8*)(bh + 96);
            v[4] = (f16)inp[(size_t)crow * DD + 0];
            v[5] = (f16)inp[(size_t)crow * DD + 1];
            v[6] = (f16)inp[(size_t)crow * DD + 2];
            v[7] = (f16)0.f;
        }
        af[3] = v;
    }

    // ---- phase A: r-gate and u-gate MFMAs interleaved ----
    f32x4 accR[7], accU[7];
    z7(accR);
    z7(accU);
    mma_unit2_nb(af, Wp2, Wp2 + UNIT_W, l, accR, accU);

    // ---- r-gate epilogue: rst = sigmoid(accR + bg1[col]) * st -> LDS ----
    #pragma unroll
    for (int j = 0; j < 7; ++j) {
        const int col = j * 16 + lr;
        if (col >= UU) continue;
        const float bR = bg1[col];
        #pragma unroll
        for (int r = 0; r < 4; ++r) {
            const int grow = rb + lk * 4 + r;
            const int lrow = lbase + lk * 4 + r;
            if (grow < M) {
                const float stv = (float)st_s[lrow * UP + col];
                const float sg = fast_sigmoid(accR[j][r] + bR);
                rst_s[lrow * UP + col] = (f16)(sg * stv);
            }
        }
    }
    if (l < 16) {
        const int grow2 = rb + l;
        const int lrow2 = lbase + l;
        if (grow2 < M) {
            rst_s[lrow2 * UP + 100] = (f16)inp[(size_t)grow2 * DD + 0];
            rst_s[lrow2 * UP + 101] = (f16)inp[(size_t)grow2 * DD + 1];
            rst_s[lrow2 * UP + 102] = (f16)inp[(size_t)grow2 * DD + 2];
            rst_s[lrow2 * UP + 103] = (f16)0.f;
        }
    }

    // ---- u-gate epilogue: u = sigmoid(accU + bg1[100+col]) in regs ----
    f16x4 uh[7];
    #pragma unroll
    for (int j = 0; j < 7; ++j) {
        const int col = j * 16 + lr;
        const float bU = (col < UU) ? bg1[UU + col] : 0.f;
        #pragma unroll
        for (int r = 0; r < 4; ++r)
            uh[j][r] = (f16)fast_sigmoid(accU[j][r] + bU);
    }

    // ---- rst A-frags from LDS (same-wave write->read, DS in-order) ----
    f16x8 af2[4];
    #pragma unroll
    for (int s = 0; s < 3; ++s)
        af2[s] = *(const f16x8*)&rst_s[(lbase + lr) * UP + (s * 4 + lk) * 8];
    af2[3] = (lk == 0) ? *(const f16x8*)&rst_s[(lbase + lr) * UP + 96]
                       : (f16x8)(f16)0.f;

    // ---- candidate + final output ----
    f32x4 acc[7];
    z7(acc);
    mma_unit_nb(af2, Wp2 + 2 * UNIT_W, l, acc);
    #pragma unroll
    for (int j = 0; j < 7; ++j) {
        const int col = j * 16 + lr;
        if (col >= UU) continue;
        const float bC = bg2[col];
        #pragma unroll
        for (int r = 0; r < 4; ++r) {
            const int grow = rb + lk * 4 + r;
            const int lrow = lbase + lk * 4 + r;
            if (grow < M) {
                const float c = fast_tanh(acc[j][r] + bC);
                const float u = (float)uh[j][r];
                const float stv = (float)st_s[lrow * UP + col];
                out[(size_t)grow * UU + col] = u * stv + (1.f - u) * c;
            }
        }
    }
}

// ---------------------------------------------------------------------------
extern "C" void kernel_launch(void* const* d_in, const int* in_sizes, int n_in,
                              void* d_out, int out_size, void* d_ws, size_t ws_size,
                              hipStream_t stream)
{
    const float* inputs   = (const float*)d_in[0];
    const float* state    = (const float*)d_in[1];
    const int*   src      = (const int*)  d_in[2];
    const int*   dst      = (const int*)  d_in[3];
    const float* Wl       = (const float*)d_in[4];
    const float* Wr       = (const float*)d_in[5];
    const float* att      = (const float*)d_in[6];
    const float* gat_bias = (const float*)d_in[7];
    const float* bias_gc  = (const float*)d_in[8];
    const float* Wg1      = (const float*)d_in[9];
    const float* bg1      = (const float*)d_in[10];
    const float* Wg2      = (const float*)d_in[11];
    const float* bg2      = (const float*)d_in[12];

    const int E = in_sizes[2];
    const int B = in_sizes[1] / (NN * UU);
    const int M = B * NN;
    const int Etot = E + NN;
    const int mb = (M + 63) / 64;

    char* ws = (char*)d_ws;
    f16* Wp   = (f16*)ws;
    int* offs = (int*)(ws + 5 * UNIT_W * sizeof(f16));
    int* cnt  = offs + (NN + 1);
    int* eidx = cnt + NN;
    int* ddst = eidx + (Etot + 64);
    f16* xl_h = (f16*)(ws + (256 << 10));
    f16* xr_h = xl_h + (size_t)M * UP;
    f16* st_h = xr_h + (size_t)M * UP;
    float* out = (float*)d_out;

    // L1: weight pack + CSR count (raw)
    prep_k<<<PACK_BLOCKS + NN, 256, 0, stream>>>(Wl, Wr, Wg1, Wg2, Wp,
                                                 dst, E, cnt);
    // L2: CSR fill (self-scanned) + xl/xr GEMM
    mid_k<<<NN + mb, 256, 0, stream>>>(src, dst, E, cnt, offs, eidx, ddst,
                                       state, inputs, Wp, xl_h, xr_h, M);
    // L3: GAT P2-P4 -> st
    gat2h_k<<<dim3(B, 2), GT, 0, stream>>>(xl_h, xr_h, offs, eidx, ddst,
                                           att, gat_bias, bias_gc, st_h);
    // L4: GRU -> out
    gru3_k<<<mb, 256, 0, stream>>>(st_h, inputs,
        Wp + 2 * (size_t)UNIT_W, bg1, bg2, out, M);
}